// Round 4
// baseline (127.283 us; speedup 1.0000x reference)
//
#include <hip/hip_runtime.h>

// PartitionPadding: out[m][p][:] = feat[starts[m]+p][:] if p < count[m] else 0.
// B=2048, MAX_ATOMS=640, D=64. Pure data movement: 256MB read + 335.5MB write.
//
// One block per molecule, all 2048 blocks resident (8/CU). Per block: s,e read
// once; 40-iter loop, 4KB moved/iter, additive addressing, 4x unroll for
// memory ILP. Nontemporal load/store (read-once / write-once streams).

#define BATCH 2048
#define MAXA  640
#define DF    64
#define ROWF4 16            // float4 per row (64 floats)

typedef float f4 __attribute__((ext_vector_type(4)));  // native vec for nontemporal builtins

// starts[] via parallel boundary detection on the sorted indicator.
__global__ void pp_starts_kernel(const int* __restrict__ ind, int N,
                                 int* __restrict__ starts) {
    int stride = gridDim.x * blockDim.x;
    for (int i = blockIdx.x * blockDim.x + threadIdx.x; i < N; i += stride) {
        int cur  = ind[i];
        int prev = (i == 0) ? -1 : ind[i - 1];
        if (cur != prev) {
            for (int m = prev + 1; m <= cur; ++m) starts[m] = i;
        }
        if (i == N - 1) {
            for (int m = cur + 1; m <= BATCH; ++m) starts[m] = N;
        }
    }
}

// One block per molecule. 256 threads; thread handles (p0 = tid>>4, q = tid&15)
// then strides p by 16 rows per iteration, 40 iterations total.
__global__ __launch_bounds__(256) void pp_gather_kernel(
        const f4* __restrict__ feat,
        const int* __restrict__ starts,
        f4* __restrict__ out) {
    const unsigned m   = blockIdx.x;
    const unsigned tid = threadIdx.x;
    const unsigned p0  = tid >> 4;    // 0..15
    const unsigned q   = tid & 15u;   // float4 within row

    const int s   = starts[m];
    const int cnt = starts[m + 1] - s;   // atoms in this molecule

    const f4* src = feat + (unsigned)(s + (int)p0) * ROWF4 + q;
    f4*       dst = out + m * (MAXA * ROWF4) + p0 * ROWF4 + q;

    int p = (int)p0;
    #pragma unroll 4
    for (int it = 0; it < MAXA / 16; ++it) {
        f4 v = (f4){0.f, 0.f, 0.f, 0.f};
        if (p < cnt) v = __builtin_nontemporal_load(src);
        __builtin_nontemporal_store(v, dst);
        p   += 16;
        src += 16 * ROWF4;
        dst += 16 * ROWF4;
    }
}

extern "C" void kernel_launch(void* const* d_in, const int* in_sizes, int n_in,
                              void* d_out, int out_size, void* d_ws, size_t ws_size,
                              hipStream_t stream) {
    const float* feat = (const float*)d_in[0];
    const int*   ind  = (const int*)d_in[1];
    float*       out  = (float*)d_out;
    int*         starts = (int*)d_ws;   // BATCH+1 ints

    const int N = in_sizes[0] / DF;

    // 1) starts via parallel boundary detect (~4MB reads, ~1-2us)
    {
        int blocks = min((N + 255) / 256, 4096);
        pp_starts_kernel<<<blocks, 256, 0, stream>>>(ind, N, starts);
    }

    // 2) per-molecule streaming gather+pad: every output element written
    {
        pp_gather_kernel<<<BATCH, 256, 0, stream>>>(
            (const f4*)feat, starts, (f4*)out);
    }
}